// Round 3
// baseline (606.852 us; speedup 1.0000x reference)
//
#include <hip/hip_runtime.h>

typedef __attribute__((ext_vector_type(4))) float f32x4;
typedef __attribute__((ext_vector_type(8))) short bf16x8;
typedef __attribute__((ext_vector_type(8))) unsigned short u16x8;
typedef __attribute__((ext_vector_type(4))) unsigned short u16x4;

#define DEV static __device__ __forceinline__

// sizes fixed by the problem
#define BQ 4
#define SQ 2048
#define DM 1024
#define HH 16
#define DK 64
#define MM (BQ * SQ)   // 8192

DEV unsigned short f2bf(float f) {
    unsigned int u = __builtin_bit_cast(unsigned int, f);
    u += 0x7fffu + ((u >> 16) & 1u);               // RNE
    return (unsigned short)(u >> 16);
}

DEV void gll16(const void* g, void* l) {           // async global->LDS, 16B/lane
    __builtin_amdgcn_global_load_lds(
        (const __attribute__((address_space(1))) unsigned int*)g,
        (__attribute__((address_space(3))) unsigned int*)l, 16, 0, 0);
}

// swizzles: XOR row bits into byte bits 4.. to break same-bank column reads
#define SWZ64(b)  ((b) ^ ((((b) >> 6) & 3) << 4))   // row stride 64B
#define SWZ128(b) ((b) ^ ((((b) >> 7) & 7) << 4))   // row stride 128B
#define SWZ256(b) ((b) ^ ((((b) >> 8) & 7) << 4))   // row stride 256B

// ---------------------------------------------------------------------------
// C = A @ W^T + bias.  A:[8192x1024] , W:[1024x1024] fp32 row-major.
// MODE 0: A fp32, C bf16 laid out [B,H,S,Dk]        (Q, K)
// MODE 1: A fp32, C bf16 laid out [B,H,Dk,S]        (V transposed)
// MODE 2: A bf16, C fp32 laid out [8192,1024]       (final projection)
// 128x128 tile, BK=32, 4 waves each computing 64x64 via 16x16x32 bf16 MFMA.
// ---------------------------------------------------------------------------
template <int MODE>
__global__ __launch_bounds__(256, 2)
void gemm_bt(const void* __restrict__ Av, const float* __restrict__ Wf,
             const float* __restrict__ bias, void* __restrict__ Cv)
{
    __shared__ unsigned short As[128 * 32];
    __shared__ unsigned short Bs[128 * 32];
    char* Asb = (char*)As;
    char* Bsb = (char*)Bs;

    const int tid = threadIdx.x, lane = tid & 63, wid = tid >> 6;
    const int l15 = lane & 15, lg = lane >> 4;
    const int wr = wid >> 1, wc = wid & 1;
    const int m0 = blockIdx.x * 128, n0 = blockIdx.y * 128;
    const int sr = tid >> 1, sc = (tid & 1) * 16;     // staging row / col-elem

    f32x4 acc[4][4];
#pragma unroll
    for (int i = 0; i < 4; ++i)
#pragma unroll
        for (int j = 0; j < 4; ++j) acc[i][j] = (f32x4){0.f, 0.f, 0.f, 0.f};

    for (int kt = 0; kt < 32; ++kt) {
        const int k0 = kt * 32;
        u16x8 av0, av1, bv0, bv1;
        if (MODE == 2) {
            const unsigned short* Ap =
                (const unsigned short*)Av + (size_t)(m0 + sr) * DM + k0 + sc;
            av0 = *(const u16x8*)Ap;
            av1 = *(const u16x8*)(Ap + 8);
        } else {
            const float* Ap = (const float*)Av + (size_t)(m0 + sr) * DM + k0 + sc;
            f32x4 a0 = *(const f32x4*)Ap,       a1 = *(const f32x4*)(Ap + 4);
            f32x4 a2 = *(const f32x4*)(Ap + 8), a3 = *(const f32x4*)(Ap + 12);
#pragma unroll
            for (int i = 0; i < 4; ++i) {
                av0[i] = f2bf(a0[i]); av0[4 + i] = f2bf(a1[i]);
                av1[i] = f2bf(a2[i]); av1[4 + i] = f2bf(a3[i]);
            }
        }
        {
            const float* Bp = Wf + (size_t)(n0 + sr) * DM + k0 + sc;
            f32x4 b0 = *(const f32x4*)Bp,       b1 = *(const f32x4*)(Bp + 4);
            f32x4 b2 = *(const f32x4*)(Bp + 8), b3 = *(const f32x4*)(Bp + 12);
#pragma unroll
            for (int i = 0; i < 4; ++i) {
                bv0[i] = f2bf(b0[i]); bv0[4 + i] = f2bf(b1[i]);
                bv1[i] = f2bf(b2[i]); bv1[4 + i] = f2bf(b3[i]);
            }
        }
        __syncthreads();                       // prev-iter reads done
        const int lb = sr * 64 + sc * 2;
        *(u16x8*)(Asb + SWZ64(lb))      = av0;
        *(u16x8*)(Asb + SWZ64(lb + 16)) = av1;
        *(u16x8*)(Bsb + SWZ64(lb))      = bv0;
        *(u16x8*)(Bsb + SWZ64(lb + 16)) = bv1;
        __syncthreads();                       // staging visible

        bf16x8 af[4], bfr[4];
#pragma unroll
        for (int mi = 0; mi < 4; ++mi) {
            int o = (wr * 64 + mi * 16 + l15) * 64 + lg * 16;
            af[mi] = *(const bf16x8*)(Asb + SWZ64(o));
        }
#pragma unroll
        for (int ni = 0; ni < 4; ++ni) {
            int o = (wc * 64 + ni * 16 + l15) * 64 + lg * 16;
            bfr[ni] = *(const bf16x8*)(Bsb + SWZ64(o));
        }
#pragma unroll
        for (int mi = 0; mi < 4; ++mi)
#pragma unroll
            for (int ni = 0; ni < 4; ++ni)
                acc[mi][ni] = __builtin_amdgcn_mfma_f32_16x16x32_bf16(
                    af[mi], bfr[ni], acc[mi][ni], 0, 0, 0);
    }

    // epilogue: C row = m0+wr*64+mi*16+lg*4+j, col = n0+wc*64+ni*16+l15
#pragma unroll
    for (int ni = 0; ni < 4; ++ni) {
        const int n = n0 + wc * 64 + ni * 16 + l15;
        const float bb = bias[n];
#pragma unroll
        for (int mi = 0; mi < 4; ++mi) {
            const int mbase = m0 + wr * 64 + mi * 16 + lg * 4;
            if (MODE == 2) {
                float* C = (float*)Cv;
#pragma unroll
                for (int j = 0; j < 4; ++j)
                    C[(size_t)(mbase + j) * DM + n] = acc[mi][ni][j] + bb;
            } else if (MODE == 0) {
                unsigned short* C = (unsigned short*)Cv;
                const int h = n >> 6, d = n & 63;
#pragma unroll
                for (int j = 0; j < 4; ++j) {
                    const int m = mbase + j, b = m >> 11, s = m & 2047;
                    C[(((size_t)(b * HH + h)) * SQ + s) * DK + d] =
                        f2bf(acc[mi][ni][j] + bb);
                }
            } else {  // MODE 1: V transposed [B,H,Dk,S]; 4 consecutive s -> 8B store
                unsigned short* C = (unsigned short*)Cv;
                const int h = n >> 6, d = n & 63;
                u16x4 pk;
#pragma unroll
                for (int j = 0; j < 4; ++j) pk[j] = f2bf(acc[mi][ni][j] + bb);
                const int m = mbase, b = m >> 11, s = m & 2047;
                *(u16x4*)&C[(((size_t)(b * HH + h)) * DK + d) * SQ + s] = pk;
            }
        }
    }
}

// ---------------------------------------------------------------------------
// Flash attention, quirk: softmax on UNSCALED scores, /sqrt(Dk)=8 after.
// grid = (S/128, B*H); 4 waves; wave owns 32 q-rows. KV tiles of 128.
// K LDS [128][64], Vt LDS [64][128] staged via global_load_lds with
// pre-swizzled global source; per-wave P tile [32][128] bf16.
// ---------------------------------------------------------------------------
__global__ __launch_bounds__(256, 2)
void flash_attn(const unsigned short* __restrict__ Qb,
                const unsigned short* __restrict__ Kb,
                const unsigned short* __restrict__ Vtb,
                unsigned short* __restrict__ outA)
{
    __shared__ unsigned short Ks[128 * 64];      // 16KB
    __shared__ unsigned short Vs[64 * 128];      // 16KB
    __shared__ unsigned short Ps[4 * 32 * 128];  // 32KB (8KB per wave, private)
    char* Ksb = (char*)Ks;
    char* Vsb = (char*)Vs;

    const int tid = threadIdx.x, lane = tid & 63, wid = tid >> 6;
    const int l15 = lane & 15, lg = lane >> 4;
    const int q0 = blockIdx.x * 128;
    const int bh = blockIdx.y;
    const unsigned short* Qp = Qb + (size_t)bh * SQ * DK;
    const unsigned short* Kp = Kb + (size_t)bh * SQ * DK;
    const unsigned short* Vp = Vtb + (size_t)bh * DK * SQ;
    char* Pwb = (char*)Ps + wid * 8192;

    // Q fragments held in registers for the whole kernel
    bf16x8 qf[2][2];
#pragma unroll
    for (int mi = 0; mi < 2; ++mi)
#pragma unroll
        for (int ki = 0; ki < 2; ++ki)
            qf[mi][ki] = *(const bf16x8*)&Qp[(size_t)(q0 + wid * 32 + mi * 16 + l15) * DK +
                                             ki * 32 + lg * 8];

    f32x4 O[2][4];
    float mrow[2][4], lrow[2][4];
#pragma unroll
    for (int mi = 0; mi < 2; ++mi)
#pragma unroll
        for (int j = 0; j < 4; ++j) { mrow[mi][j] = -3.0e38f; lrow[mi][j] = 0.f; }
#pragma unroll
    for (int mi = 0; mi < 2; ++mi)
#pragma unroll
        for (int di = 0; di < 4; ++di) O[mi][di] = (f32x4){0.f, 0.f, 0.f, 0.f};

    const float L2E = 1.44269504089f;

    for (int kt = 0; kt < 16; ++kt) {
        const int kv0 = kt * 128;
        __syncthreads();  // everyone done reading Ks/Vs from previous tile
        // ---- stage K [128][64] (contiguous) and Vt [64][128] (row chunks) ----
#pragma unroll
        for (int i = 0; i < 4; ++i) {
            const int p = (wid * 4 + i) * 1024 + lane * 16;  // physical LDS byte
            {   // K: logical == global-linear; pre-swizzle the source
                const int Lb = SWZ128(p);
                gll16((const char*)Kp + (size_t)kv0 * 128 + Lb,
                      Ksb + (wid * 4 + i) * 1024);
            }
            {   // Vt: row d = p>>8, 256B per row; global row stride 4096B
                const int d = p >> 8;
                const int cb = (p ^ ((d & 7) << 4)) & 255;
                gll16((const char*)Vp + (size_t)d * 4096 + kv0 * 2 + cb,
                      Vsb + (wid * 4 + i) * 1024);
            }
        }
        asm volatile("s_waitcnt vmcnt(0)" ::: "memory");
        __syncthreads();  // tiles ready

        // ---- S = Q K^T (32 q-rows x 128 kv), f32 acc ----
        f32x4 Sf[2][8];
#pragma unroll
        for (int mi = 0; mi < 2; ++mi)
#pragma unroll
            for (int ni = 0; ni < 8; ++ni) Sf[mi][ni] = (f32x4){0.f, 0.f, 0.f, 0.f};
#pragma unroll
        for (int ki = 0; ki < 2; ++ki) {
#pragma unroll
            for (int ni = 0; ni < 8; ++ni) {
                const int o = (ni * 16 + l15) * 128 + ki * 64 + lg * 16;
                const bf16x8 kf = *(const bf16x8*)(Ksb + SWZ128(o));
                Sf[0][ni] = __builtin_amdgcn_mfma_f32_16x16x32_bf16(qf[0][ki], kf, Sf[0][ni], 0, 0, 0);
                Sf[1][ni] = __builtin_amdgcn_mfma_f32_16x16x32_bf16(qf[1][ki], kf, Sf[1][ni], 0, 0, 0);
            }
        }

        // ---- online softmax (unscaled scores), rows = (lg*4+j) per 16-tile ----
#pragma unroll
        for (int mi = 0; mi < 2; ++mi) {
#pragma unroll
            for (int j = 0; j < 4; ++j) {
                float tm = Sf[mi][0][j];
#pragma unroll
                for (int ni = 1; ni < 8; ++ni) tm = fmaxf(tm, Sf[mi][ni][j]);
#pragma unroll
                for (int d = 1; d < 16; d <<= 1) tm = fmaxf(tm, __shfl_xor(tm, d));
                const float mo = mrow[mi][j];
                const float mn = fmaxf(mo, tm);
                const float corr = __builtin_exp2f((mo - mn) * L2E);
                float rs = 0.f;
#pragma unroll
                for (int ni = 0; ni < 8; ++ni) {
                    const float p = __builtin_exp2f((Sf[mi][ni][j] - mn) * L2E);
                    Sf[mi][ni][j] = p;
                    rs += p;
                }
#pragma unroll
                for (int d = 1; d < 16; d <<= 1) rs += __shfl_xor(rs, d);
                lrow[mi][j] = lrow[mi][j] * corr + rs;
                mrow[mi][j] = mn;
#pragma unroll
                for (int di = 0; di < 4; ++di) O[mi][di][j] *= corr;
            }
        }

        // ---- P -> bf16 -> per-wave LDS (swizzled) ----
#pragma unroll
        for (int mi = 0; mi < 2; ++mi) {
#pragma unroll
            for (int j = 0; j < 4; ++j) {
                const int row = mi * 16 + lg * 4 + j;
#pragma unroll
                for (int ni = 0; ni < 8; ++ni) {
                    const int o = row * 256 + (ni * 16 + l15) * 2;
                    *(unsigned short*)(Pwb + (o ^ ((row & 7) << 4))) = f2bf(Sf[mi][ni][j]);
                }
            }
        }

        // ---- O += P V  (A = P [q x kv], B = V [kv x d] read from Vt) ----
#pragma unroll
        for (int kk = 0; kk < 4; ++kk) {
            bf16x8 pf[2];
#pragma unroll
            for (int mi = 0; mi < 2; ++mi) {
                const int o = (mi * 16 + l15) * 256 + kk * 64 + lg * 16;
                pf[mi] = *(const bf16x8*)(Pwb + SWZ256(o));
            }
#pragma unroll
            for (int di = 0; di < 4; ++di) {
                const int o = (di * 16 + l15) * 256 + kk * 64 + lg * 16;
                const bf16x8 vf = *(const bf16x8*)(Vsb + SWZ256(o));
                O[0][di] = __builtin_amdgcn_mfma_f32_16x16x32_bf16(pf[0], vf, O[0][di], 0, 0, 0);
                O[1][di] = __builtin_amdgcn_mfma_f32_16x16x32_bf16(pf[1], vf, O[1][di], 0, 0, 0);
            }
        }
    }

    // ---- epilogue: out = O / (8 * l); write bf16 [B,S,H*Dk] ----
    const int b = bh >> 4, h = bh & 15;
#pragma unroll
    for (int mi = 0; mi < 2; ++mi) {
#pragma unroll
        for (int j = 0; j < 4; ++j) {
            const float inv = 1.f / (8.f * lrow[mi][j]);
            const int q = q0 + wid * 32 + mi * 16 + lg * 4 + j;
#pragma unroll
            for (int di = 0; di < 4; ++di)
                outA[((size_t)(b * SQ + q)) * DM + h * DK + di * 16 + l15] =
                    f2bf(O[mi][di][j] * inv);
        }
    }
}

// ---------------------------------------------------------------------------
extern "C" void kernel_launch(void* const* d_in, const int* in_sizes, int n_in,
                              void* d_out, int out_size, void* d_ws, size_t ws_size,
                              hipStream_t stream)
{
    (void)in_sizes; (void)n_in; (void)out_size; (void)ws_size;
    const float* q  = (const float*)d_in[0];
    const float* k  = (const float*)d_in[1];
    const float* v  = (const float*)d_in[2];
    const float* WQ = (const float*)d_in[3];
    const float* bQ = (const float*)d_in[4];
    const float* WK = (const float*)d_in[5];
    const float* bK = (const float*)d_in[6];
    const float* WV = (const float*)d_in[7];
    const float* bV = (const float*)d_in[8];
    const float* W0 = (const float*)d_in[9];
    const float* b0 = (const float*)d_in[10];

    unsigned short* ws = (unsigned short*)d_ws;
    const size_t NEL = (size_t)MM * DM;          // 8M elements per buffer
    unsigned short* Qb  = ws;
    unsigned short* Kb  = ws + NEL;
    unsigned short* Vtb = ws + 2 * NEL;
    unsigned short* Ab  = ws + 3 * NEL;          // attention output, bf16 [B,S,D]

    dim3 blk(256);
    dim3 gg(MM / 128, DM / 128);                 // 64 x 8
    hipLaunchKernelGGL((gemm_bt<0>), gg, blk, 0, stream, (const void*)q, WQ, bQ, (void*)Qb);
    hipLaunchKernelGGL((gemm_bt<0>), gg, blk, 0, stream, (const void*)k, WK, bK, (void*)Kb);
    hipLaunchKernelGGL((gemm_bt<1>), gg, blk, 0, stream, (const void*)v, WV, bV, (void*)Vtb);
    hipLaunchKernelGGL(flash_attn, dim3(SQ / 128, BQ * HH), blk, 0, stream, Qb, Kb, Vtb, Ab);
    hipLaunchKernelGGL((gemm_bt<2>), gg, blk, 0, stream, (const void*)Ab, W0, b0, d_out);
}

// Round 4
// 595.050 us; speedup vs baseline: 1.0198x; 1.0198x over previous
//
#include <hip/hip_runtime.h>

typedef __attribute__((ext_vector_type(4))) float f32x4;
typedef __attribute__((ext_vector_type(8))) short bf16x8;
typedef __attribute__((ext_vector_type(8))) unsigned short u16x8;
typedef __attribute__((ext_vector_type(4))) unsigned short u16x4;

#define DEV static __device__ __forceinline__

// sizes fixed by the problem
#define BQ 4
#define SQ 2048
#define DM 1024
#define HH 16
#define DK 64
#define MM (BQ * SQ)   // 8192

DEV unsigned short f2bf(float f) {
    unsigned int u = __builtin_bit_cast(unsigned int, f);
    u += 0x7fffu + ((u >> 16) & 1u);               // RNE
    return (unsigned short)(u >> 16);
}

DEV void gll16(const void* g, void* l) {           // async global->LDS, 16B/lane
    __builtin_amdgcn_global_load_lds(
        (const __attribute__((address_space(1))) unsigned int*)g,
        (__attribute__((address_space(3))) unsigned int*)l, 16, 0, 0);
}

// swizzles: XOR row bits into byte bits 4.. to break same-bank column reads
#define SWZ64(b)  ((b) ^ ((((b) >> 6) & 3) << 4))   // row stride 64B
#define SWZ128(b) ((b) ^ ((((b) >> 7) & 7) << 4))   // row stride 128B
#define SWZ256(b) ((b) ^ ((((b) >> 8) & 7) << 4))   // row stride 256B

// ---------------------------------------------------------------------------
// C = A @ W^T + bias.  A:[8192x1024] , W:[1024x1024] fp32 row-major.
// MODE 0: A fp32, C bf16 laid out [B,H,S,Dk]        (Q, K)
// MODE 1: A fp32, C bf16 laid out [B,H,Dk,S]        (V transposed)
// MODE 2: A bf16, C fp32 laid out [8192,1024]       (final projection)
// 128x128 tile, BK=32, 4 waves each computing 64x64 via 16x16x32 bf16 MFMA.
// ---------------------------------------------------------------------------
template <int MODE>
__global__ __launch_bounds__(256, 2)
void gemm_bt(const void* __restrict__ Av, const float* __restrict__ Wf,
             const float* __restrict__ bias, void* __restrict__ Cv)
{
    __shared__ unsigned short As[128 * 32];
    __shared__ unsigned short Bs[128 * 32];
    char* Asb = (char*)As;
    char* Bsb = (char*)Bs;

    const int tid = threadIdx.x, lane = tid & 63, wid = tid >> 6;
    const int l15 = lane & 15, lg = lane >> 4;
    const int wr = wid >> 1, wc = wid & 1;
    const int m0 = blockIdx.x * 128, n0 = blockIdx.y * 128;
    const int sr = tid >> 1, sc = (tid & 1) * 16;     // staging row / col-elem

    f32x4 acc[4][4];
#pragma unroll
    for (int i = 0; i < 4; ++i)
#pragma unroll
        for (int j = 0; j < 4; ++j) acc[i][j] = (f32x4){0.f, 0.f, 0.f, 0.f};

    for (int kt = 0; kt < 32; ++kt) {
        const int k0 = kt * 32;
        u16x8 av0, av1, bv0, bv1;
        if (MODE == 2) {
            const unsigned short* Ap =
                (const unsigned short*)Av + (size_t)(m0 + sr) * DM + k0 + sc;
            av0 = *(const u16x8*)Ap;
            av1 = *(const u16x8*)(Ap + 8);
        } else {
            const float* Ap = (const float*)Av + (size_t)(m0 + sr) * DM + k0 + sc;
            f32x4 a0 = *(const f32x4*)Ap,       a1 = *(const f32x4*)(Ap + 4);
            f32x4 a2 = *(const f32x4*)(Ap + 8), a3 = *(const f32x4*)(Ap + 12);
#pragma unroll
            for (int i = 0; i < 4; ++i) {
                av0[i] = f2bf(a0[i]); av0[4 + i] = f2bf(a1[i]);
                av1[i] = f2bf(a2[i]); av1[4 + i] = f2bf(a3[i]);
            }
        }
        {
            const float* Bp = Wf + (size_t)(n0 + sr) * DM + k0 + sc;
            f32x4 b0 = *(const f32x4*)Bp,       b1 = *(const f32x4*)(Bp + 4);
            f32x4 b2 = *(const f32x4*)(Bp + 8), b3 = *(const f32x4*)(Bp + 12);
#pragma unroll
            for (int i = 0; i < 4; ++i) {
                bv0[i] = f2bf(b0[i]); bv0[4 + i] = f2bf(b1[i]);
                bv1[i] = f2bf(b2[i]); bv1[4 + i] = f2bf(b3[i]);
            }
        }
        __syncthreads();                       // prev-iter reads done
        const int lb = sr * 64 + sc * 2;
        *(u16x8*)(Asb + SWZ64(lb))      = av0;
        *(u16x8*)(Asb + SWZ64(lb + 16)) = av1;
        *(u16x8*)(Bsb + SWZ64(lb))      = bv0;
        *(u16x8*)(Bsb + SWZ64(lb + 16)) = bv1;
        __syncthreads();                       // staging visible

        bf16x8 af[4], bfr[4];
#pragma unroll
        for (int mi = 0; mi < 4; ++mi) {
            int o = (wr * 64 + mi * 16 + l15) * 64 + lg * 16;
            af[mi] = *(const bf16x8*)(Asb + SWZ64(o));
        }
#pragma unroll
        for (int ni = 0; ni < 4; ++ni) {
            int o = (wc * 64 + ni * 16 + l15) * 64 + lg * 16;
            bfr[ni] = *(const bf16x8*)(Bsb + SWZ64(o));
        }
#pragma unroll
        for (int mi = 0; mi < 4; ++mi)
#pragma unroll
            for (int ni = 0; ni < 4; ++ni)
                acc[mi][ni] = __builtin_amdgcn_mfma_f32_16x16x32_bf16(
                    af[mi], bfr[ni], acc[mi][ni], 0, 0, 0);
    }

    // epilogue: C row = m0+wr*64+mi*16+lg*4+j, col = n0+wc*64+ni*16+l15
#pragma unroll
    for (int ni = 0; ni < 4; ++ni) {
        const int n = n0 + wc * 64 + ni * 16 + l15;
        const float bb = bias[n];
#pragma unroll
        for (int mi = 0; mi < 4; ++mi) {
            const int mbase = m0 + wr * 64 + mi * 16 + lg * 4;
            if (MODE == 2) {
                float* C = (float*)Cv;
#pragma unroll
                for (int j = 0; j < 4; ++j)
                    C[(size_t)(mbase + j) * DM + n] = acc[mi][ni][j] + bb;
            } else if (MODE == 0) {
                unsigned short* C = (unsigned short*)Cv;
                const int h = n >> 6, d = n & 63;
#pragma unroll
                for (int j = 0; j < 4; ++j) {
                    const int m = mbase + j, b = m >> 11, s = m & 2047;
                    C[(((size_t)(b * HH + h)) * SQ + s) * DK + d] =
                        f2bf(acc[mi][ni][j] + bb);
                }
            } else {  // MODE 1: V transposed [B,H,Dk,S]; 4 consecutive s -> 8B store
                unsigned short* C = (unsigned short*)Cv;
                const int h = n >> 6, d = n & 63;
                u16x4 pk;
#pragma unroll
                for (int j = 0; j < 4; ++j) pk[j] = f2bf(acc[mi][ni][j] + bb);
                const int m = mbase, b = m >> 11, s = m & 2047;
                *(u16x4*)&C[(((size_t)(b * HH + h)) * DK + d) * SQ + s] = pk;
            }
        }
    }
}

// ---------------------------------------------------------------------------
// Flash attention, quirk: softmax on UNSCALED scores, /sqrt(Dk)=8 after.
// grid = (S/128, B*H); 4 waves; wave owns 32 q-rows. KV tiles of 128.
// K LDS [128][64], Vt LDS [64][128] staged via global_load_lds with
// pre-swizzled global source; per-wave P tile [32][128] bf16.
// ---------------------------------------------------------------------------
__global__ __launch_bounds__(256, 2)
void flash_attn(const unsigned short* __restrict__ Qb,
                const unsigned short* __restrict__ Kb,
                const unsigned short* __restrict__ Vtb,
                unsigned short* __restrict__ outA)
{
    __shared__ unsigned short Ks[128 * 64];      // 16KB
    __shared__ unsigned short Vs[64 * 128];      // 16KB
    __shared__ unsigned short Ps[4 * 32 * 128];  // 32KB (8KB per wave, private)
    char* Ksb = (char*)Ks;
    char* Vsb = (char*)Vs;

    const int tid = threadIdx.x, lane = tid & 63, wid = tid >> 6;
    const int l15 = lane & 15, lg = lane >> 4;
    const int q0 = blockIdx.x * 128;
    const int bh = blockIdx.y;
    const unsigned short* Qp = Qb + (size_t)bh * SQ * DK;
    const unsigned short* Kp = Kb + (size_t)bh * SQ * DK;
    const unsigned short* Vp = Vtb + (size_t)bh * DK * SQ;
    char* Pwb = (char*)Ps + wid * 8192;

    // Q fragments held in registers for the whole kernel
    bf16x8 qf[2][2];
#pragma unroll
    for (int mi = 0; mi < 2; ++mi)
#pragma unroll
        for (int ki = 0; ki < 2; ++ki)
            qf[mi][ki] = *(const bf16x8*)&Qp[(size_t)(q0 + wid * 32 + mi * 16 + l15) * DK +
                                             ki * 32 + lg * 8];

    f32x4 O[2][4];
    float mrow[2][4], lrow[2][4];
#pragma unroll
    for (int mi = 0; mi < 2; ++mi)
#pragma unroll
        for (int j = 0; j < 4; ++j) { mrow[mi][j] = -3.0e38f; lrow[mi][j] = 0.f; }
#pragma unroll
    for (int mi = 0; mi < 2; ++mi)
#pragma unroll
        for (int di = 0; di < 4; ++di) O[mi][di] = (f32x4){0.f, 0.f, 0.f, 0.f};

    const float L2E = 1.44269504089f;

    for (int kt = 0; kt < 16; ++kt) {
        const int kv0 = kt * 128;
        __syncthreads();  // everyone done reading Ks/Vs from previous tile
        // ---- stage K [128][64] (contiguous) and Vt [64][128] (row chunks) ----
#pragma unroll
        for (int i = 0; i < 4; ++i) {
            const int p = (wid * 4 + i) * 1024 + lane * 16;  // physical LDS byte
            {   // K: logical == global-linear; pre-swizzle the source
                const int Lb = SWZ128(p);
                gll16((const char*)Kp + (size_t)kv0 * 128 + Lb,
                      Ksb + (wid * 4 + i) * 1024);
            }
            {   // Vt: row d = p>>8, 256B per row; global row stride 4096B
                const int d = p >> 8;
                const int cb = (p ^ ((d & 7) << 4)) & 255;
                gll16((const char*)Vp + (size_t)d * 4096 + kv0 * 2 + cb,
                      Vsb + (wid * 4 + i) * 1024);
            }
        }
        asm volatile("s_waitcnt vmcnt(0)" ::: "memory");
        __syncthreads();  // tiles ready

        // ---- S = Q K^T (32 q-rows x 128 kv), f32 acc ----
        f32x4 Sf[2][8];
#pragma unroll
        for (int mi = 0; mi < 2; ++mi)
#pragma unroll
            for (int ni = 0; ni < 8; ++ni) Sf[mi][ni] = (f32x4){0.f, 0.f, 0.f, 0.f};
#pragma unroll
        for (int ki = 0; ki < 2; ++ki) {
#pragma unroll
            for (int ni = 0; ni < 8; ++ni) {
                const int o = (ni * 16 + l15) * 128 + ki * 64 + lg * 16;
                const bf16x8 kf = *(const bf16x8*)(Ksb + SWZ128(o));
                Sf[0][ni] = __builtin_amdgcn_mfma_f32_16x16x32_bf16(qf[0][ki], kf, Sf[0][ni], 0, 0, 0);
                Sf[1][ni] = __builtin_amdgcn_mfma_f32_16x16x32_bf16(qf[1][ki], kf, Sf[1][ni], 0, 0, 0);
            }
        }

        // ---- online softmax (unscaled scores), rows = (lg*4+j) per 16-tile ----
#pragma unroll
        for (int mi = 0; mi < 2; ++mi) {
#pragma unroll
            for (int j = 0; j < 4; ++j) {
                float tm = Sf[mi][0][j];
#pragma unroll
                for (int ni = 1; ni < 8; ++ni) tm = fmaxf(tm, Sf[mi][ni][j]);
#pragma unroll
                for (int d = 1; d < 16; d <<= 1) tm = fmaxf(tm, __shfl_xor(tm, d));
                const float mo = mrow[mi][j];
                const float mn = fmaxf(mo, tm);
                const float corr = __builtin_exp2f((mo - mn) * L2E);
                float rs = 0.f;
#pragma unroll
                for (int ni = 0; ni < 8; ++ni) {
                    const float p = __builtin_exp2f((Sf[mi][ni][j] - mn) * L2E);
                    Sf[mi][ni][j] = p;
                    rs += p;
                }
#pragma unroll
                for (int d = 1; d < 16; d <<= 1) rs += __shfl_xor(rs, d);
                lrow[mi][j] = lrow[mi][j] * corr + rs;
                mrow[mi][j] = mn;
#pragma unroll
                for (int di = 0; di < 4; ++di) O[mi][di][j] *= corr;
            }
        }

        // ---- P -> bf16 -> per-wave LDS (swizzled) ----
#pragma unroll
        for (int mi = 0; mi < 2; ++mi) {
#pragma unroll
            for (int j = 0; j < 4; ++j) {
                const int row = mi * 16 + lg * 4 + j;
#pragma unroll
                for (int ni = 0; ni < 8; ++ni) {
                    const int o = row * 256 + (ni * 16 + l15) * 2;
                    *(unsigned short*)(Pwb + (o ^ ((row & 7) << 4))) = f2bf(Sf[mi][ni][j]);
                }
            }
        }

        // ---- O += P V  (A = P [q x kv], B = V [kv x d] read from Vt) ----
#pragma unroll
        for (int kk = 0; kk < 4; ++kk) {
            bf16x8 pf[2];
#pragma unroll
            for (int mi = 0; mi < 2; ++mi) {
                const int o = (mi * 16 + l15) * 256 + kk * 64 + lg * 16;
                pf[mi] = *(const bf16x8*)(Pwb + SWZ256(o));
            }
#pragma unroll
            for (int di = 0; di < 4; ++di) {
                const int o = (di * 16 + l15) * 256 + kk * 64 + lg * 16;
                const bf16x8 vf = *(const bf16x8*)(Vsb + SWZ256(o));
                O[0][di] = __builtin_amdgcn_mfma_f32_16x16x32_bf16(pf[0], vf, O[0][di], 0, 0, 0);
                O[1][di] = __builtin_amdgcn_mfma_f32_16x16x32_bf16(pf[1], vf, O[1][di], 0, 0, 0);
            }
        }
    }

    // ---- epilogue: out = O / (8 * l); write bf16 [B,S,H*Dk] ----
    const int b = bh >> 4, h = bh & 15;
#pragma unroll
    for (int mi = 0; mi < 2; ++mi) {
#pragma unroll
        for (int j = 0; j < 4; ++j) {
            const float inv = 1.f / (8.f * lrow[mi][j]);
            const int q = q0 + wid * 32 + mi * 16 + lg * 4 + j;
#pragma unroll
            for (int di = 0; di < 4; ++di)
                outA[((size_t)(b * SQ + q)) * DM + h * DK + di * 16 + l15] =
                    f2bf(O[mi][di][j] * inv);
        }
    }
}

// ---------------------------------------------------------------------------
extern "C" void kernel_launch(void* const* d_in, const int* in_sizes, int n_in,
                              void* d_out, int out_size, void* d_ws, size_t ws_size,
                              hipStream_t stream)
{
    (void)in_sizes; (void)n_in; (void)out_size; (void)ws_size;
    const float* q  = (const float*)d_in[0];
    const float* k  = (const float*)d_in[1];
    const float* v  = (const float*)d_in[2];
    const float* WQ = (const float*)d_in[3];
    const float* bQ = (const float*)d_in[4];
    const float* WK = (const float*)d_in[5];
    const float* bK = (const float*)d_in[6];
    const float* WV = (const float*)d_in[7];
    const float* bV = (const float*)d_in[8];
    const float* W0 = (const float*)d_in[9];
    const float* b0 = (const float*)d_in[10];

    unsigned short* ws = (unsigned short*)d_ws;
    const size_t NEL = (size_t)MM * DM;          // 8M elements per buffer
    unsigned short* Qb  = ws;
    unsigned short* Kb  = ws + NEL;
    unsigned short* Vtb = ws + 2 * NEL;
    unsigned short* Ab  = ws + 3 * NEL;          // attention output, bf16 [B,S,D]

    dim3 blk(256);
    dim3 gg(MM / 128, DM / 128);                 // 64 x 8
    hipLaunchKernelGGL((gemm_bt<0>), gg, blk, 0, stream, (const void*)q, WQ, bQ, (void*)Qb);
    hipLaunchKernelGGL((gemm_bt<0>), gg, blk, 0, stream, (const void*)k, WK, bK, (void*)Kb);
    hipLaunchKernelGGL((gemm_bt<1>), gg, blk, 0, stream, (const void*)v, WV, bV, (void*)Vtb);
    hipLaunchKernelGGL(flash_attn, dim3(SQ / 128, BQ * HH), blk, 0, stream, Qb, Kb, Vtb, Ab);
    hipLaunchKernelGGL((gemm_bt<2>), gg, blk, 0, stream, (const void*)Ab, W0, b0, d_out);
}